// Round 17
// baseline (157.204 us; speedup 1.0000x reference)
//
#include <hip/hip_runtime.h>

#define B_ 4
#define L_ 256
#define D_ 1024
#define D4_ 256
#define R_ 8

typedef __attribute__((ext_vector_type(8))) __bf16 bf16x8;
typedef __attribute__((ext_vector_type(4))) __bf16 bf16x4;
typedef __attribute__((ext_vector_type(4))) float f32x4;
typedef __attribute__((ext_vector_type(2))) float f32x2;

__device__ __forceinline__ float4 ld4(const float* p){ return *reinterpret_cast<const float4*>(p); }
__device__ __forceinline__ void st4(float* p, float4 v){ *reinterpret_cast<float4*>(p) = v; }

// tanh via hardware exp2: ~8 VALU ops, abs err ~1e-7
__device__ __forceinline__ float fast_tanh(float x){
  x = fminf(fmaxf(x, -9.f), 9.f);
  float e = exp2f(x * 2.885390081777927f);     // e^{2x}
  return (e - 1.f) * __builtin_amdgcn_rcpf(e + 1.f);
}

// packed tanh on 2 floats: tanh(x) = 1 - 2/(e^{2x}+1). Pure C vector ops.
__device__ __forceinline__ f32x2 fast_tanh2(f32x2 x){
  const f32x2 kk = {2.885390081777927f, 2.885390081777927f};
  f32x2 kx = x * kk;
  float c0 = fminf(fmaxf(kx[0], -26.f), 26.f);
  float c1 = fminf(fmaxf(kx[1], -26.f), 26.f);
  f32x2 e = { exp2f(c0), exp2f(c1) };
  f32x2 den = e + (f32x2){1.f, 1.f};
  f32x2 r = { __builtin_amdgcn_rcpf(den[0]), __builtin_amdgcn_rcpf(den[1]) };
  return (f32x2){-2.f, -2.f} * r + (f32x2){1.f, 1.f};
}

__device__ __forceinline__ unsigned pack_bf16(float a, float b){
  __bf16 x = (__bf16)a, y = (__bf16)b;
  unsigned short ux = __builtin_bit_cast(unsigned short, x);
  unsigned short uy = __builtin_bit_cast(unsigned short, y);
  return (unsigned)ux | ((unsigned)uy << 16);
}

// ---------------------------------------------------------------------------
// Inline prefix-mask decode: stride sniff + per-element nonzero test.
// ---------------------------------------------------------------------------
__device__ __forceinline__ int mask_stride(const unsigned char* mask){
  const unsigned int* w = (const unsigned int*)mask;
  unsigned int w0 = w[0];
  if (w0 == 0x01010101u) return 1;
  if (w0 == 0x3F803F80u) return 2;
  if (w0 == 0x3C003C00u) return 2;
  if (w0 == 0x3F800000u) return 4;
  if (w0 == 1u) return (w[1] == 1u) ? 4 : 8;
  if (w0 == 0u && w[1] == 0x3FF00000u) return 8;
  return 1;
}
__device__ __forceinline__ bool mask_at(const unsigned char* mask, int stride, int idx){
  const unsigned char* e = mask + (size_t)idx * stride;
  unsigned char nz = 0;
  for (int s = 0; s < stride; s++) nz |= e[s];
  return nz != 0;
}

// ---------------------------------------------------------------------------
// Mega-prep: [0,512) X->bf16 | [512,1024) linear weights | [1024,4096) conv_w
// | [4096,4607) PE table | 4607: Wo -> Wo16[16][256] bf16 (rows 8..15 zero).
// ---------------------------------------------------------------------------
__global__ __launch_bounds__(256) void k_megaprep(
    const float* __restrict__ X, const unsigned char* __restrict__ mask,
    __bf16* __restrict__ xu, __bf16* __restrict__ xm,
    const float* __restrict__ cw, __bf16* __restrict__ wbc,
    const float* __restrict__ w0, const float* __restrict__ w1,
    const float* __restrict__ w2, const float* __restrict__ w3,
    __bf16* __restrict__ o0, __bf16* __restrict__ o1,
    __bf16* __restrict__ o2, __bf16* __restrict__ o3,
    __bf16* __restrict__ pe,
    const float* __restrict__ Wo, __bf16* __restrict__ wot16)
{
  int blk = blockIdx.x, tid = threadIdx.x;
  if (blk < 512){
    int idx = blk*256 + tid;
    int row = idx >> 7, c8 = (idx & 127) << 3;
    int stride = mask_stride(mask);
    bool keep = mask_at(mask, stride, row);
    const float* src = X + ((size_t)row << 10) + c8;
    bf16x8 u, m;
    #pragma unroll
    for (int e = 0; e < 8; e++){
      float f = src[e];
      u[e] = (__bf16)f;
      m[e] = keep ? (__bf16)f : (__bf16)0.f;
    }
    *reinterpret_cast<bf16x8*>(xu + ((size_t)row<<10) + c8) = u;
    *reinterpret_cast<bf16x8*>(xm + ((size_t)row<<10) + c8) = m;
  } else if (blk < 1024){
    int sub = blk - 512;
    const float* src; __bf16* dst;
    switch (sub >> 7){
      case 0: src = w0; dst = o0; break;
      case 1: src = w1; dst = o1; break;
      case 2: src = w2; dst = o2; break;
      default: src = w3; dst = o3; break;
    }
    int idx = (sub & 127)*256 + tid;
    const float* p = src + (size_t)idx*8;
    bf16x8 v;
    #pragma unroll
    for (int e = 0; e < 8; e++) v[e] = (__bf16)p[e];
    *reinterpret_cast<bf16x8*>(dst + (size_t)idx*8) = v;
  } else if (blk < 4096){
    int idx = (blk - 1024)*256 + tid;
    int layer = idx / 262144;
    int rem = idx & 262143;
    int o = rem >> 8, c4 = (rem & 255) << 2;
    const float* src = cw + (((size_t)layer*1024 + o)*1024 + c4)*3;
    float4 f0 = ld4(src), f1 = ld4(src+4), f2 = ld4(src+8);
    float tv[3][4] = {
      {f0.x, f0.w, f1.z, f2.y},
      {f0.y, f1.x, f1.w, f2.z},
      {f0.z, f1.y, f2.x, f2.w}
    };
    #pragma unroll
    for (int t = 0; t < 3; t++){
      bf16x4 v;
      #pragma unroll
      for (int e = 0; e < 4; e++) v[e] = (__bf16)tv[t][e];
      *reinterpret_cast<bf16x4*>(wbc + ((size_t)(layer*3+t)*1024 + o)*1024 + c4) = v;
    }
  } else if (blk < 4607){
    int t = blk - 4096;
    float posv = (float)(255 - t);
    const float c = -9.210340371976184f / (float)D_;
    for (int m = tid; m < D_/2; m += 256){
      float div = __expf((float)(2*m) * c);
      float val = posv * div;
      pe[((size_t)t<<10) + 2*m]     = (__bf16)__sinf(val);
      pe[((size_t)t<<10) + 2*m + 1] = (__bf16)__cosf(val);
    }
  } else {
    // Wo16[r][k], rows 8..15 zero-padded
    for (int e = tid; e < 4096; e += 256){
      int r = e >> 8, k = e & 255;
      wot16[e] = (r < 8) ? (__bf16)Wo[(r << 8) + k] : (__bf16)0.f;
    }
  }
}

// ---------------------------------------------------------------------------
// MFMA GEMM tile body (64x64). Staging via global_load_lds (linear dest +
// pre-swizzled source). A falls back to guarded register path if row0+64 > M.
// ---------------------------------------------------------------------------
__device__ __forceinline__ void gemm_body(__bf16 (*As)[64], __bf16 (*Bs)[64],
                                          const __bf16* __restrict__ A,
                                          const __bf16* __restrict__ Bw,
                                          const float* __restrict__ bias,
                                          const float* __restrict__ bias2,
                                          float* __restrict__ C,
                                          float* __restrict__ Ct,
                                          int M, int N, int Kd,
                                          int row0, int col0, int tid)
{
  int lane = tid & 63, wave = tid >> 6;
  int wv = __builtin_amdgcn_readfirstlane(wave);
  int wm = (wave >> 1) << 5, wn = (wave & 1) << 5;
  __bf16* as_flat = &As[0][0];
  __bf16* bs_flat = &Bs[0][0];
  bool safeA = (row0 + 64 <= M);
  f32x4 acc[2][2] = {};
  for (int k0 = 0; k0 < Kd; k0 += 64){
    if (safeA){
      #pragma unroll
      for (int it = 0; it < 2; it++){
        int sbase = (wv*2 + it) << 6;        // wave-uniform
        int s = sbase + lane;
        int r = s >> 3, cs = s & 7;
        const __bf16* gp = A + (size_t)(row0 + r)*Kd + k0 + ((cs ^ (r & 7)) << 3);
        __builtin_amdgcn_global_load_lds(gp, as_flat + ((size_t)sbase << 3), 16, 0, 0);
      }
    } else {
      for (int idx = tid; idx < 512; idx += 256){
        int r = idx >> 3, c = idx & 7;
        int row = row0 + r;
        bf16x8 v = {};
        if (row < M) v = *reinterpret_cast<const bf16x8*>(A + (size_t)row*Kd + k0 + (c<<3));
        *reinterpret_cast<bf16x8*>(&As[r][(c ^ (r & 7)) << 3]) = v;
      }
    }
    #pragma unroll
    for (int it = 0; it < 2; it++){
      int sbase = (wv*2 + it) << 6;          // wave-uniform
      int s = sbase + lane;
      int r = s >> 3, cs = s & 7;
      const __bf16* gp = Bw + (size_t)(col0 + r)*Kd + k0 + ((cs ^ (r & 7)) << 3);
      __builtin_amdgcn_global_load_lds(gp, bs_flat + ((size_t)sbase << 3), 16, 0, 0);
    }
    __syncthreads();
    #pragma unroll
    for (int kk = 0; kk < 2; kk++){
      int kc = (kk << 2) + (lane >> 4);
      int ra0 = wm + (lane & 15), ra1 = ra0 + 16;
      int rb0 = wn + (lane & 15), rb1 = rb0 + 16;
      bf16x8 a0 = *reinterpret_cast<const bf16x8*>(&As[ra0][(kc ^ (ra0 & 7)) << 3]);
      bf16x8 a1 = *reinterpret_cast<const bf16x8*>(&As[ra1][(kc ^ (ra1 & 7)) << 3]);
      bf16x8 b0 = *reinterpret_cast<const bf16x8*>(&Bs[rb0][(kc ^ (rb0 & 7)) << 3]);
      bf16x8 b1 = *reinterpret_cast<const bf16x8*>(&Bs[rb1][(kc ^ (rb1 & 7)) << 3]);
      acc[0][0] = __builtin_amdgcn_mfma_f32_16x16x32_bf16(a0, b0, acc[0][0], 0, 0, 0);
      acc[0][1] = __builtin_amdgcn_mfma_f32_16x16x32_bf16(a0, b1, acc[0][1], 0, 0, 0);
      acc[1][0] = __builtin_amdgcn_mfma_f32_16x16x32_bf16(a1, b0, acc[1][0], 0, 0, 0);
      acc[1][1] = __builtin_amdgcn_mfma_f32_16x16x32_bf16(a1, b1, acc[1][1], 0, 0, 0);
    }
    __syncthreads();
  }
  #pragma unroll
  for (int mi = 0; mi < 2; mi++)
    #pragma unroll
    for (int ni = 0; ni < 2; ni++){
      int col = col0 + wn + (ni << 4) + (lane & 15);
      float bv = bias ? ((col < 256) ? bias[col] : bias2[col - 256]) : 0.f;
      int rowb = row0 + wm + (mi << 4) + ((lane >> 4) << 2);
      if (Ct){
        float* dst = Ct + ((size_t)(col >> 2) << 11) + (col & 3);
        #pragma unroll
        for (int e = 0; e < 4; e++){
          int row = rowb + e;
          if (row < M) dst[row << 2] = acc[mi][ni][e] + bv;
        }
      } else {
        #pragma unroll
        for (int e = 0; e < 4; e++){
          int row = rowb + e;
          if (row < M) C[(size_t)row*N + col] = acc[mi][ni][e] + bv;
        }
      }
    }
}

// ---------------------------------------------------------------------------
// Batched tail GEMMs: [0,64) cum | [64,192) c_lin/p_lin fused | [192,224) pos.
// ---------------------------------------------------------------------------
__global__ __launch_bounds__(256) void k_gemm3(
    const __bf16* __restrict__ Xb_u, const __bf16* __restrict__ Wcum_b,
    const float* __restrict__ bcum, float* __restrict__ cum,
    const __bf16* __restrict__ hb_fin, const __bf16* __restrict__ Wc_b,
    const float* __restrict__ bc, const float* __restrict__ bp,
    float* __restrict__ cp_lin,
    const __bf16* __restrict__ pe_b, const __bf16* __restrict__ Wr_b,
    const float* __restrict__ br, float* __restrict__ pos_t)
{
  __shared__ __align__(16) __bf16 As[64][64];
  __shared__ __align__(16) __bf16 Bs[64][64];
  int blk = blockIdx.x, tid = threadIdx.x;
  if (blk < 64){
    gemm_body(As, Bs, Xb_u, Wcum_b, bcum, bcum, cum, nullptr,
              1024, 256, 1024, (blk & 15) << 6, (blk >> 4) << 6, tid);
  } else if (blk < 192){
    int s = blk - 64;
    gemm_body(As, Bs, hb_fin, Wc_b, bc, bp, cp_lin, nullptr,
              1024, 512, 1024, (s & 15) << 6, (s >> 4) << 6, tid);
  } else {
    int s = blk - 192;
    gemm_body(As, Bs, pe_b, Wr_b, br, br, nullptr, pos_t,
              511, 256, 1024, (s & 7) << 6, (s >> 3) << 6, tid);
  }
}

// ---------------------------------------------------------------------------
// Cross-term GEMMs for LN-stat decomposition:
// [0,64) G1 | [64,192) G2 = ci·pos | [192,320) G3 = pj·pos.
// ---------------------------------------------------------------------------
__global__ __launch_bounds__(256) void k_gemm_cross(
    const __bf16* __restrict__ ci_bf, const __bf16* __restrict__ pj_bf,
    const __bf16* __restrict__ pos_bf,
    float* __restrict__ G1, float* __restrict__ G2, float* __restrict__ G3)
{
  __shared__ __align__(16) __bf16 As[64][64];
  __shared__ __align__(16) __bf16 Bs[64][64];
  int blk = blockIdx.x, tid = threadIdx.x;
  if (blk < 64){
    int b = blk >> 4, s = blk & 15;
    gemm_body(As, Bs, ci_bf + ((size_t)b << 16), pj_bf + ((size_t)b << 16),
              nullptr, nullptr, G1 + ((size_t)b << 16), nullptr,
              256, 256, 256, (s & 3) << 6, (s >> 2) << 6, tid);
  } else if (blk < 192){
    int s = blk - 64;
    gemm_body(As, Bs, ci_bf, pos_bf, nullptr, nullptr, G2, nullptr,
              1024, 512, 256, (s & 15) << 6, (s >> 4) << 6, tid);
  } else {
    int s = blk - 192;
    gemm_body(As, Bs, pj_bf, pos_bf, nullptr, nullptr, G3, nullptr,
              1024, 512, 256, (s & 15) << 6, (s >> 4) << 6, tid);
  }
}

// ---------------------------------------------------------------------------
// Conv layer, z-split x4 (256 channels each), XCD-contiguous block swizzle.
// B-stage + A-interior rows via global_load_lds; halo rows via register path.
// ---------------------------------------------------------------------------
__global__ __launch_bounds__(256) void k_conv_mfma(const __bf16* __restrict__ hb,
                                                   const __bf16* __restrict__ wbc,
                                                   __bf16* __restrict__ y, int layer)
{
  __shared__ __align__(16) __bf16 As[66][64];
  __shared__ __align__(16) __bf16 Bs[3][64][64];
  int tid = threadIdx.x;
  int lane = tid & 63, wave = tid >> 6;
  int wv = __builtin_amdgcn_readfirstlane(wave);
  int wm = (wave >> 1) << 5, wn = (wave & 1) << 5;
  int n = blockIdx.x;
  int swz = (n & 7)*128 + (n >> 3);      // XCD k handles contiguous swz chunk
  int bx = swz & 15, oy = (swz >> 4) & 15, z = swz >> 8;
  int b = bx >> 2, l0 = (bx & 3) << 6;
  int o0 = oy << 6;
  __bf16* as_flat = &As[0][0];
  __bf16* bs_flat = &Bs[0][0][0];
  f32x4 acc[2][2] = {};
  for (int cc = 0; cc < 4; cc++){
    int c0 = (z << 8) + (cc << 6);
    #pragma unroll
    for (int it = 0; it < 6; it++){
      int m = wv*6 + it;
      int s = (m << 6) + lane;
      int t = s >> 9, r = (s >> 3) & 63, c_ = s & 7;
      const __bf16* gp = wbc + ((size_t)((layer*3 + t) << 10) + o0 + r)*1024
                       + c0 + ((c_ ^ (r & 7)) << 3);
      __builtin_amdgcn_global_load_lds(gp, bs_flat + ((size_t)m << 9), 16, 0, 0);
    }
    #pragma unroll
    for (int it = 0; it < 2; it++){
      int sbase = (wv*2 + it) << 6;
      int s = sbase + lane;
      int r = 1 + (s >> 3), c = s & 7;
      const __bf16* gp = hb + (((size_t)(b<<8) + l0 - 1 + r) << 10)
                       + c0 + ((c ^ (r & 7)) << 3);
      __builtin_amdgcn_global_load_lds(gp, as_flat + 64 + ((size_t)sbase << 3), 16, 0, 0);
    }
    if (tid < 16){
      int rr = (tid >> 3) ? 65 : 0;
      int c = tid & 7;
      int l = l0 - 1 + rr;
      bf16x8 v = {};
      if (l >= 0 && l < L_)
        v = *reinterpret_cast<const bf16x8*>(hb + (((size_t)(b<<8) + l) << 10) + c0 + (c<<3));
      *reinterpret_cast<bf16x8*>(&As[rr][(c ^ (rr & 7)) << 3]) = v;
    }
    __syncthreads();
    #pragma unroll
    for (int t = 0; t < 3; t++){
      #pragma unroll
      for (int kk = 0; kk < 2; kk++){
        int kc = (kk << 2) + (lane >> 4);
        int ra0 = wm + (lane & 15) + t, ra1 = ra0 + 16;
        int rb0 = wn + (lane & 15),     rb1 = rb0 + 16;
        bf16x8 a0 = *reinterpret_cast<const bf16x8*>(&As[ra0][(kc ^ (ra0 & 7)) << 3]);
        bf16x8 a1 = *reinterpret_cast<const bf16x8*>(&As[ra1][(kc ^ (ra1 & 7)) << 3]);
        bf16x8 b0 = *reinterpret_cast<const bf16x8*>(&Bs[t][rb0][(kc ^ (rb0 & 7)) << 3]);
        bf16x8 b1 = *reinterpret_cast<const bf16x8*>(&Bs[t][rb1][(kc ^ (rb1 & 7)) << 3]);
        acc[0][0] = __builtin_amdgcn_mfma_f32_16x16x32_bf16(a0, b0, acc[0][0], 0, 0, 0);
        acc[0][1] = __builtin_amdgcn_mfma_f32_16x16x32_bf16(a0, b1, acc[0][1], 0, 0, 0);
        acc[1][0] = __builtin_amdgcn_mfma_f32_16x16x32_bf16(a1, b0, acc[1][0], 0, 0, 0);
        acc[1][1] = __builtin_amdgcn_mfma_f32_16x16x32_bf16(a1, b1, acc[1][1], 0, 0, 0);
      }
    }
    __syncthreads();
  }
  __bf16* yz = y + (size_t)z * 1048576;
  #pragma unroll
  for (int mi = 0; mi < 2; mi++)
    #pragma unroll
    for (int ni = 0; ni < 2; ni++){
      int col = o0 + wn + (ni << 4) + (lane & 15);
      #pragma unroll
      for (int e = 0; e < 4; e++){
        int rowl = wm + (mi << 4) + ((lane >> 4) << 2) + e;
        yz[(((size_t)(b<<8) + l0 + rowl) << 10) + col] = (__bf16)acc[mi][ni][e];
      }
    }
}

// ---------------------------------------------------------------------------
// LN(1024)+tanh over sum of 4 bf16 partials + bias.
// ---------------------------------------------------------------------------
__device__ __forceinline__ void ln_core4(const __bf16* y, const float* cb, int n, int tid,
                                         int lane, int wid, float* red,
                                         float4& v, float& mu, float& rstd){
  const __bf16* yr = y + ((size_t)n << 10) + tid*4;
  bf16x4 a0 = *reinterpret_cast<const bf16x4*>(yr);
  bf16x4 a1 = *reinterpret_cast<const bf16x4*>(yr + 1048576);
  bf16x4 a2 = *reinterpret_cast<const bf16x4*>(yr + 2097152);
  bf16x4 a3 = *reinterpret_cast<const bf16x4*>(yr + 3145728);
  float4 bb = ld4(cb + tid*4);
  v = make_float4((float)a0[0]+(float)a1[0]+(float)a2[0]+(float)a3[0]+bb.x,
                  (float)a0[1]+(float)a1[1]+(float)a2[1]+(float)a3[1]+bb.y,
                  (float)a0[2]+(float)a1[2]+(float)a2[2]+(float)a3[2]+bb.z,
                  (float)a0[3]+(float)a1[3]+(float)a2[3]+(float)a3[3]+bb.w);
  float s = v.x+v.y+v.z+v.w;
  #pragma unroll
  for (int m=1;m<64;m<<=1) s += __shfl_xor(s, m);
  if (lane == 0) red[wid] = s;
  __syncthreads();
  mu = (red[0]+red[1]+red[2]+red[3]) * (1.f/D_);
  float d0=v.x-mu, d1=v.y-mu, d2=v.z-mu, d3=v.w-mu;
  float ss = d0*d0+d1*d1+d2*d2+d3*d3;
  #pragma unroll
  for (int m=1;m<64;m<<=1) ss += __shfl_xor(ss, m);
  if (lane == 0) red[8+wid] = ss;
  __syncthreads();
  rstd = rsqrtf((red[8]+red[9]+red[10]+red[11]) * (1.f/D_) + 1e-5f);
}

__global__ __launch_bounds__(256) void k_ln_tanh_mid(const __bf16* __restrict__ y,
                                                     const float* __restrict__ cb,
                                                     const unsigned char* __restrict__ mask,
                                                     __bf16* __restrict__ hb)
{
  __shared__ float red[16];
  int n = blockIdx.x;
  int tid = threadIdx.x, lane = tid & 63, wid = tid >> 6;
  float4 v; float mu, rstd;
  ln_core4(y, cb, n, tid, lane, wid, red, v, mu, rstd);
  int stride = mask_stride(mask);
  float keep = mask_at(mask, stride, n) ? 1.f : 0.f;
  bf16x4 o;
  o[0] = (__bf16)(fast_tanh((v.x-mu)*rstd) * keep);
  o[1] = (__bf16)(fast_tanh((v.y-mu)*rstd) * keep);
  o[2] = (__bf16)(fast_tanh((v.z-mu)*rstd) * keep);
  o[3] = (__bf16)(fast_tanh((v.w-mu)*rstd) * keep);
  *reinterpret_cast<bf16x4*>(hb + ((size_t)n<<10) + tid*4) = o;
}

__global__ __launch_bounds__(256) void k_ln_tanh_fin(const __bf16* __restrict__ y,
                                                     const float* __restrict__ cb,
                                                     float* __restrict__ hf,
                                                     __bf16* __restrict__ hb)
{
  __shared__ float red[16];
  int n = blockIdx.x;
  int tid = threadIdx.x, lane = tid & 63, wid = tid >> 6;
  float4 v; float mu, rstd;
  ln_core4(y, cb, n, tid, lane, wid, red, v, mu, rstd);
  float t0 = fast_tanh((v.x-mu)*rstd), t1 = fast_tanh((v.y-mu)*rstd);
  float t2 = fast_tanh((v.z-mu)*rstd), t3 = fast_tanh((v.w-mu)*rstd);
  st4(&hf[((size_t)n<<10) + tid*4], make_float4(t0,t1,t2,t3));
  bf16x4 o; o[0]=(__bf16)t0; o[1]=(__bf16)t1; o[2]=(__bf16)t2; o[3]=(__bf16)t3;
  *reinterpret_cast<bf16x4*>(hb + ((size_t)n<<10) + tid*4) = o;
}

// ---------------------------------------------------------------------------
// Combine: masked cumsum + fold. ci row-major; pj transposed-packed
// pjt[k4][b][j][4]. Mask decoded to LDS flags (same b for all 4 waves).
// ---------------------------------------------------------------------------
__global__ __launch_bounds__(256) void k_combine(const float* __restrict__ cum,
                                                 const float* __restrict__ cp,
                                                 const unsigned char* __restrict__ mask,
                                                 float* __restrict__ ci,
                                                 float* __restrict__ pjt)
{
  __shared__ unsigned char mflag[256];
  int tid = threadIdx.x;
  int b = blockIdx.x >> 6;
  {
    int stride = mask_stride(mask);
    mflag[tid] = mask_at(mask, stride, (b << 8) + tid) ? 1 : 0;
  }
  __syncthreads();
  int w = blockIdx.x*4 + (tid >> 6);
  int lane = tid & 63;
  int k = w & 255;
  int rowbase = b << 8;
  float v[4], p[4];
  float run = 0.f;
  #pragma unroll
  for (int e = 0; e < 4; e++){
    int l = lane*4 + e;
    float x = cum[(((size_t)rowbase + l) << 8) + k];
    v[e] = mflag[l] ? 0.f : x;
    run += v[e]; p[e] = run;
  }
  float t = run, s = run;
  #pragma unroll
  for (int off = 1; off < 64; off <<= 1){
    float u = __shfl_up(s, off);
    if (lane >= off) s += u;
  }
  float excl = s - t;
  float total = __shfl(s, 63);
  float* pjb = pjt + (((size_t)((k >> 2)*4 + b)) << 10) + (k & 3);
  #pragma unroll
  for (int e = 0; e < 4; e++){
    int l = lane*4 + e;
    size_t row = rowbase + l;
    float f_ex = excl + p[e] - v[e];
    float b_in = total - (excl + p[e]);
    ci[(row << 8) + k] = cp[row*512 + k] + f_ex;
    pjb[l << 2] = cp[row*512 + 256 + k] - b_in;
  }
}

// ---------------------------------------------------------------------------
// Row stats + bf16 copies: wave per row. [0,1024) ci | [1024,2048) pj |
// [2048,2560) pos (row 511 zeroed).
// ---------------------------------------------------------------------------
__global__ __launch_bounds__(256) void k_rowstats(const float* __restrict__ ci,
                                                  const float* __restrict__ pjt,
                                                  const float* __restrict__ post,
                                                  __bf16* __restrict__ ci_bf,
                                                  __bf16* __restrict__ pj_bf,
                                                  __bf16* __restrict__ pos_bf,
                                                  float* __restrict__ stats)
{
  int w = blockIdx.x*4 + (threadIdx.x >> 6);
  int lane = threadIdx.x & 63;
  float4 v; __bf16* dst; float* Sp; float* Qp;
  if (w < 1024){
    v = ld4(&ci[((size_t)w << 8) + (lane << 2)]);
    dst = ci_bf + ((size_t)w << 8) + (lane << 2);
    Sp = stats + w; Qp = stats + 1024 + w;
  } else if (w < 2048){
    int row = w - 1024;
    int b = row >> 8, j = row & 255;
    v = ld4(pjt + ((size_t)lane << 12) + (b << 10) + (j << 2));
    dst = pj_bf + ((size_t)row << 8) + (lane << 2);
    Sp = stats + 2048 + row; Qp = stats + 3072 + row;
  } else {
    int d = w - 2048;
    if (d < 511) v = ld4(post + ((size_t)lane << 11) + (d << 2));
    else         v = make_float4(0.f, 0.f, 0.f, 0.f);
    dst = pos_bf + ((size_t)d << 8) + (lane << 2);
    Sp = stats + 4096 + d; Qp = stats + 4608 + d;
  }
  bf16x4 o; o[0]=(__bf16)v.x; o[1]=(__bf16)v.y; o[2]=(__bf16)v.z; o[3]=(__bf16)v.w;
  *reinterpret_cast<bf16x4*>(dst) = o;
  float s = v.x+v.y+v.z+v.w;
  float qv = v.x*v.x + v.y*v.y + v.z*v.z + v.w*v.w;
  #pragma unroll
  for (int m = 1; m < 64; m <<= 1){
    s  += __shfl_xor(s,  m);
    qv += __shfl_xor(qv, m);
  }
  if (lane == 0){ *Sp = s; *Qp = qv; }
}

// ---------------------------------------------------------------------------
// Pair kernel v11: single pass; V = tanh(LN(h)) written as bf16 into a
// 64x256 swizzled LDS tile; projection done with 8 MFMAs per wave against
// zero-padded Wo16 (fragment mappings identical to gemm_body's verified use).
// ---------------------------------------------------------------------------
__global__ __launch_bounds__(256) void k_pairs(const float* __restrict__ ci,
                                               const float* __restrict__ pjt,
                                               const float* __restrict__ post,
                                               const float* __restrict__ ln_g,
                                               const float* __restrict__ ln_b,
                                               const __bf16* __restrict__ wot16,
                                               const float* __restrict__ bo,
                                               const unsigned char* __restrict__ mask,
                                               const float* __restrict__ stats,
                                               const float* __restrict__ G1,
                                               const float* __restrict__ G2,
                                               const float* __restrict__ G3,
                                               float* __restrict__ out)
{
  __shared__ __align__(16) __bf16 V[64][256];

  int bid = blockIdx.x;
  int qtr = bid & 3;
  int bi = bid >> 2;                 // b*256 + i
  int b = bi >> 8, i = bi & 255;
  int tid = threadIdx.x;
  int jj = tid & 63, q = tid >> 6;
  int j = (qtr << 6) + jj;

  int d = i - j + 255;
  int bj = (b << 8) + j;
  const float* pjb = pjt + ((size_t)b << 10) + (j << 2);
  const float* pob = post + ((size_t)d << 2);
  const float* cbase = ci + ((size_t)bi << 8);
  int k40 = __builtin_amdgcn_readfirstlane(q << 4);   // wave-uniform k4 base

  // stats via decomposition
  float Sh = stats[bi] + stats[2048 + bj] + stats[4096 + d];
  float Qh = stats[1024 + bi] + stats[3072 + bj] + stats[4608 + d]
           + 2.f*(G1[((size_t)b << 16) + (i << 8) + j]
                + G2[((size_t)bi << 9) + d]
                + G3[((size_t)bj << 9) + d]);
  float mu = Sh * (1.f/256.f);
  float var = fmaxf(Qh * (1.f/256.f) - mu*mu, 0.f);
  float rstd = rsqrtf(var + 1e-5f);

  // V slice: this thread's 64 channels of row jj (2 k4-groups per iteration)
  f32x2 mmu = {-mu, -mu}, rr = {rstd, rstd};
  #pragma unroll
  for (int uu = 0; uu < 8; uu++){
    unsigned pk[4];
    #pragma unroll
    for (int h2 = 0; h2 < 2; h2++){
      int k4 = k40 + 2*uu + h2;
      float4 c4 = ld4(cbase + (k4 << 2));          // uniform -> scalar pipe
      float4 g4 = ld4(ln_g + (k4 << 2));           // uniform
      float4 b4 = ld4(ln_b + (k4 << 2));           // uniform
      float4 pv = ld4(pjb + ((size_t)k4 << 12));   // per-lane
      float4 ov = ld4(pob + ((size_t)k4 << 11));   // per-lane
      f32x2 hA = (f32x2){c4.x, c4.y} + (f32x2){pv.x, pv.y} + (f32x2){ov.x, ov.y};
      f32x2 hB = (f32x2){c4.z, c4.w} + (f32x2){pv.z, pv.w} + (f32x2){ov.z, ov.w};
      f32x2 gA = {g4.x, g4.y}, gB = {g4.z, g4.w};
      f32x2 bA = {b4.x, b4.y}, bB = {b4.z, b4.w};
      f32x2 vA = fast_tanh2(((hA + mmu) * rr) * gA + bA);
      f32x2 vB = fast_tanh2(((hB + mmu) * rr) * gB + bB);
      pk[2*h2]   = pack_bf16(vA[0], vA[1]);
      pk[2*h2+1] = pack_bf16(vB[0], vB[1]);
    }
    int c = (q << 3) + uu;                          // 8-ch group index 0..31
    uint4 wv = {pk[0], pk[1], pk[2], pk[3]};
    *reinterpret_cast<uint4*>(&V[jj][(c ^ (jj & 7)) << 3]) = wv;
  }
  __syncthreads();

  // projection via MFMA: wave q owns j-rows [q*16, q*16+16)
  bf16x8 bfr[8];
  #pragma unroll
  for (int s = 0; s < 8; s++){
    int kc = (s << 2) + (jj >> 4);
    bfr[s] = *reinterpret_cast<const bf16x8*>(wot16 + ((jj & 15) << 8) + (kc << 3));
  }
  f32x4 acc = {};
  #pragma unroll
  for (int s = 0; s < 8; s++){
    int kc = (s << 2) + (jj >> 4);
    int row = (q << 4) + (jj & 15);
    bf16x8 av = *reinterpret_cast<const bf16x8*>(&V[row][(kc ^ (row & 7)) << 3]);
    acc = __builtin_amdgcn_mfma_f32_16x16x32_bf16(av, bfr[s], acc, 0, 0, 0);
  }

  // epilogue: C/D mapping col=lane&15 (=r), row=(lane>>4)*4+e (j-local)
  int r = jj & 15;
  if (r < 8){
    int stride = mask_stride(mask);
    bool visi = mask_at(mask, stride, bi);
    float bor = bo[r];
    #pragma unroll
    for (int e = 0; e < 4; e++){
      int jl = (q << 4) + ((jj >> 4) << 2) + e;
      int jg = (qtr << 6) + jl;
      bool vis = visi && mask_at(mask, stride, (b << 8) + jg);
      float sc = (acc[e] + bor) * (1.f/7.5f);
      float res = vis ? fast_tanh(sc)*7.5f : -64.f;
      out[(((size_t)bi << 8) + jg)*8 + r] = res;
      if (jg == i)
        out[(size_t)B_*L_*L_*R_ + ((size_t)bi)*8 + r] = res;
    }
  }
}

// ---------------------------------------------------------------------------
extern "C" void kernel_launch(void* const* d_in, const int* in_sizes, int n_in,
                              void* d_out, int out_size, void* d_ws, size_t ws_size,
                              hipStream_t stream)
{
  const float* X      = (const float*)d_in[0];
  const float* conv_w = (const float*)d_in[1];
  const float* conv_b = (const float*)d_in[2];
  const float* Wc     = (const float*)d_in[3];
  const float* bc     = (const float*)d_in[4];
  const float* Wp     = (const float*)d_in[5];
  const float* bp     = (const float*)d_in[6];
  const float* Wcum   = (const float*)d_in[7];
  const float* bcum   = (const float*)d_in[8];
  const float* Wr     = (const float*)d_in[9];
  const float* br     = (const float*)d_in[10];
  const float* ln_g   = (const float*)d_in[11];
  const float* ln_b   = (const float*)d_in[12];
  const float* Wo     = (const float*)d_in[13];
  const float* bo     = (const float*)d_in[14];
  const unsigned char* mask = (const unsigned char*)d_in[15];
  float* out = (float*)d_out;

  char* base = (char*)d_ws;
  auto alloc = [&](size_t bytes){ char* p = base; base += (bytes + 255) & ~(size_t)255; return p; };
  __bf16* Xb_u    = (__bf16*)alloc(2097152);
  __bf16* Xb_m    = (__bf16*)alloc(2097152);
  __bf16* Wbc     = (__bf16*)alloc(18874368);
  __bf16* Wcum_b  = (__bf16*)alloc(524288);
  __bf16* Wc_b    = (__bf16*)alloc(524288);   // contiguous with Wp_b -> [512][1024]
  __bf16* Wp_b    = (__bf16*)alloc(524288);
  __bf16* Wr_b    = (__bf16*)alloc(524288);
  __bf16* pe_b    = (__bf16*)alloc(1046528);
  __bf16* ypart   = (__bf16*)alloc(8388608);  // 4 x [1024][1024] bf16 partials
  __bf16* hb_mid  = (__bf16*)alloc(2097152);
  __bf16* hb_fin  = (__bf16*)alloc(2097152);
  float*  cum     = (float*) alloc(1048576);
  float*  cp_lin  = (float*) alloc(2097152);  // [1024][512]
  float*  ci_c    = (float*) alloc(1048576);  // [b][i][256]
  float*  pj_t    = (float*) alloc(1048576);  // [k4][b][j][4]
  float*  pos_t   = (float*) alloc(524288);   // [k4][512 d][4]
  __bf16* ci_bf   = (__bf16*)alloc(524288);   // [1024][256]
  __bf16* pj_bf   = (__bf16*)alloc(524288);   // [1024][256]
  __bf16* pos_bf  = (__bf16*)alloc(262144);   // [512][256]
  float*  statsB  = (float*) alloc(20480);    // S/Q rows (5120 f32)
  float*  G1      = (float*) alloc(1048576);  // [4][256][256]
  float*  G2      = (float*) alloc(2097152);  // [1024][512]
  float*  G3      = (float*) alloc(2097152);  // [1024][512]
  __bf16* wot16   = (__bf16*)alloc(8192);     // [16][256] bf16, rows 8..15 zero
  (void)Wp_b;

  float* h_out = out + (size_t)B_*L_*L_*R_ + (size_t)B_*L_*R_;

  k_megaprep<<<4608, 256, 0, stream>>>(X, mask, Xb_u, Xb_m, conv_w, Wbc,
                                       Wcum, Wc, Wp, Wr, Wcum_b, Wc_b, Wp_b, Wr_b,
                                       pe_b, Wo, wot16);

  // conv stack (z-split x4, XCD swizzle, glds staging, bias folded into LN)
  k_conv_mfma<<<1024, 256, 0, stream>>>(Xb_m,   Wbc, ypart, 0);
  k_ln_tanh_mid<<<B_*L_, 256, 0, stream>>>(ypart, conv_b,        mask, hb_mid);
  k_conv_mfma<<<1024, 256, 0, stream>>>(hb_mid, Wbc, ypart, 1);
  k_ln_tanh_mid<<<B_*L_, 256, 0, stream>>>(ypart, conv_b + 1024, mask, hb_mid);
  k_conv_mfma<<<1024, 256, 0, stream>>>(hb_mid, Wbc, ypart, 2);
  k_ln_tanh_fin<<<B_*L_, 256, 0, stream>>>(ypart, conv_b + 2048, h_out, hb_fin);

  // batched tail GEMMs: cum | c_lin/p_lin | pos
  k_gemm3<<<224, 256, 0, stream>>>(Xb_u, Wcum_b, bcum, cum,
                                   hb_fin, Wc_b, bc, bp, cp_lin,
                                   pe_b, Wr_b, br, pos_t);

  // cumsum + fold
  k_combine<<<256, 256, 0, stream>>>(cum, cp_lin, mask, ci_c, pj_t);

  // row stats + bf16 copies, then cross-term GEMMs
  k_rowstats<<<640, 256, 0, stream>>>(ci_c, pj_t, pos_t, ci_bf, pj_bf, pos_bf, statsB);
  k_gemm_cross<<<320, 256, 0, stream>>>(ci_bf, pj_bf, pos_bf, G1, G2, G3);

  // pairs (single pass, MFMA projection)
  k_pairs<<<B_*L_*4, 256, 0, stream>>>(ci_c, pj_t, pos_t, ln_g, ln_b, wot16, bo,
                                       mask, statsB, G1, G2, G3, out);
}

// Round 18
// 147.654 us; speedup vs baseline: 1.0647x; 1.0647x over previous
//
#include <hip/hip_runtime.h>

#define B_ 4
#define L_ 256
#define D_ 1024
#define D4_ 256
#define R_ 8

typedef __attribute__((ext_vector_type(8))) __bf16 bf16x8;
typedef __attribute__((ext_vector_type(4))) __bf16 bf16x4;
typedef __attribute__((ext_vector_type(4))) float f32x4;
typedef __attribute__((ext_vector_type(2))) float f32x2;

__device__ __forceinline__ float4 ld4(const float* p){ return *reinterpret_cast<const float4*>(p); }
__device__ __forceinline__ void st4(float* p, float4 v){ *reinterpret_cast<float4*>(p) = v; }

// tanh via hardware exp2: ~8 VALU ops, abs err ~1e-7
__device__ __forceinline__ float fast_tanh(float x){
  x = fminf(fmaxf(x, -9.f), 9.f);
  float e = exp2f(x * 2.885390081777927f);     // e^{2x}
  return (e - 1.f) * __builtin_amdgcn_rcpf(e + 1.f);
}

// packed tanh on 2 floats: tanh(x) = 1 - 2/(e^{2x}+1). Pure C vector ops.
__device__ __forceinline__ f32x2 fast_tanh2(f32x2 x){
  const f32x2 kk = {2.885390081777927f, 2.885390081777927f};
  f32x2 kx = x * kk;
  float c0 = fminf(fmaxf(kx[0], -26.f), 26.f);
  float c1 = fminf(fmaxf(kx[1], -26.f), 26.f);
  f32x2 e = { exp2f(c0), exp2f(c1) };
  f32x2 den = e + (f32x2){1.f, 1.f};
  f32x2 r = { __builtin_amdgcn_rcpf(den[0]), __builtin_amdgcn_rcpf(den[1]) };
  return (f32x2){-2.f, -2.f} * r + (f32x2){1.f, 1.f};
}

// ---------------------------------------------------------------------------
// Inline prefix-mask decode: stride sniff + per-element nonzero test.
// ---------------------------------------------------------------------------
__device__ __forceinline__ int mask_stride(const unsigned char* mask){
  const unsigned int* w = (const unsigned int*)mask;
  unsigned int w0 = w[0];
  if (w0 == 0x01010101u) return 1;
  if (w0 == 0x3F803F80u) return 2;
  if (w0 == 0x3C003C00u) return 2;
  if (w0 == 0x3F800000u) return 4;
  if (w0 == 1u) return (w[1] == 1u) ? 4 : 8;
  if (w0 == 0u && w[1] == 0x3FF00000u) return 8;
  return 1;
}
__device__ __forceinline__ bool mask_at(const unsigned char* mask, int stride, int idx){
  const unsigned char* e = mask + (size_t)idx * stride;
  unsigned char nz = 0;
  for (int s = 0; s < stride; s++) nz |= e[s];
  return nz != 0;
}

// ---------------------------------------------------------------------------
// Mega-prep: [0,512) X->bf16 | [512,1024) linear weights | [1024,4096) conv_w
// | [4096,4607) PE table | 4607: Wo -> wot pair-interleaved transpose
// wot[k2*16 + r*2 + p] = Wo[r][2*k2+p]  (matches k_pairs consumer).
// ---------------------------------------------------------------------------
__global__ __launch_bounds__(256) void k_megaprep(
    const float* __restrict__ X, const unsigned char* __restrict__ mask,
    __bf16* __restrict__ xu, __bf16* __restrict__ xm,
    const float* __restrict__ cw, __bf16* __restrict__ wbc,
    const float* __restrict__ w0, const float* __restrict__ w1,
    const float* __restrict__ w2, const float* __restrict__ w3,
    __bf16* __restrict__ o0, __bf16* __restrict__ o1,
    __bf16* __restrict__ o2, __bf16* __restrict__ o3,
    __bf16* __restrict__ pe,
    const float* __restrict__ Wo, float* __restrict__ wot)
{
  int blk = blockIdx.x, tid = threadIdx.x;
  if (blk < 512){
    int idx = blk*256 + tid;
    int row = idx >> 7, c8 = (idx & 127) << 3;
    int stride = mask_stride(mask);
    bool keep = mask_at(mask, stride, row);
    const float* src = X + ((size_t)row << 10) + c8;
    bf16x8 u, m;
    #pragma unroll
    for (int e = 0; e < 8; e++){
      float f = src[e];
      u[e] = (__bf16)f;
      m[e] = keep ? (__bf16)f : (__bf16)0.f;
    }
    *reinterpret_cast<bf16x8*>(xu + ((size_t)row<<10) + c8) = u;
    *reinterpret_cast<bf16x8*>(xm + ((size_t)row<<10) + c8) = m;
  } else if (blk < 1024){
    int sub = blk - 512;
    const float* src; __bf16* dst;
    switch (sub >> 7){
      case 0: src = w0; dst = o0; break;
      case 1: src = w1; dst = o1; break;
      case 2: src = w2; dst = o2; break;
      default: src = w3; dst = o3; break;
    }
    int idx = (sub & 127)*256 + tid;
    const float* p = src + (size_t)idx*8;
    bf16x8 v;
    #pragma unroll
    for (int e = 0; e < 8; e++) v[e] = (__bf16)p[e];
    *reinterpret_cast<bf16x8*>(dst + (size_t)idx*8) = v;
  } else if (blk < 4096){
    int idx = (blk - 1024)*256 + tid;
    int layer = idx / 262144;
    int rem = idx & 262143;
    int o = rem >> 8, c4 = (rem & 255) << 2;
    const float* src = cw + (((size_t)layer*1024 + o)*1024 + c4)*3;
    float4 f0 = ld4(src), f1 = ld4(src+4), f2 = ld4(src+8);
    float tv[3][4] = {
      {f0.x, f0.w, f1.z, f2.y},
      {f0.y, f1.x, f1.w, f2.z},
      {f0.z, f1.y, f2.x, f2.w}
    };
    #pragma unroll
    for (int t = 0; t < 3; t++){
      bf16x4 v;
      #pragma unroll
      for (int e = 0; e < 4; e++) v[e] = (__bf16)tv[t][e];
      *reinterpret_cast<bf16x4*>(wbc + ((size_t)(layer*3+t)*1024 + o)*1024 + c4) = v;
    }
  } else if (blk < 4607){
    int t = blk - 4096;
    float posv = (float)(255 - t);
    const float c = -9.210340371976184f / (float)D_;
    for (int m = tid; m < D_/2; m += 256){
      float div = __expf((float)(2*m) * c);
      float val = posv * div;
      pe[((size_t)t<<10) + 2*m]     = (__bf16)__sinf(val);
      pe[((size_t)t<<10) + 2*m + 1] = (__bf16)__cosf(val);
    }
  } else {
    // wot[e]: e = k2*16 + r*2 + p  ->  Wo[r*256 + 2*k2 + p]
    for (int e = tid; e < 2048; e += 256)
      wot[e] = Wo[(((e >> 1) & 7) << 8) + ((e >> 4) << 1) + (e & 1)];
  }
}

// ---------------------------------------------------------------------------
// MFMA GEMM tile body (64x64). Staging via global_load_lds (linear dest +
// pre-swizzled source; content-identical to the ds_write path). A falls back
// to a guarded register path when the row block overruns M.
// ---------------------------------------------------------------------------
__device__ __forceinline__ void gemm_body(__bf16 (*As)[64], __bf16 (*Bs)[64],
                                          const __bf16* __restrict__ A,
                                          const __bf16* __restrict__ Bw,
                                          const float* __restrict__ bias,
                                          const float* __restrict__ bias2,
                                          float* __restrict__ C,
                                          float* __restrict__ Ct,
                                          int M, int N, int Kd,
                                          int row0, int col0, int tid)
{
  int lane = tid & 63, wave = tid >> 6;
  int wv = __builtin_amdgcn_readfirstlane(wave);
  int wm = (wave >> 1) << 5, wn = (wave & 1) << 5;
  __bf16* as_flat = &As[0][0];
  __bf16* bs_flat = &Bs[0][0];
  bool safeA = (row0 + 64 <= M);
  f32x4 acc[2][2] = {};
  for (int k0 = 0; k0 < Kd; k0 += 64){
    if (safeA){
      #pragma unroll
      for (int it = 0; it < 2; it++){
        int sbase = (wv*2 + it) << 6;        // wave-uniform
        int s = sbase + lane;
        int r = s >> 3, cs = s & 7;
        const __bf16* gp = A + (size_t)(row0 + r)*Kd + k0 + ((cs ^ (r & 7)) << 3);
        __builtin_amdgcn_global_load_lds(gp, as_flat + ((size_t)sbase << 3), 16, 0, 0);
      }
    } else {
      for (int idx = tid; idx < 512; idx += 256){
        int r = idx >> 3, c = idx & 7;
        int row = row0 + r;
        bf16x8 v = {};
        if (row < M) v = *reinterpret_cast<const bf16x8*>(A + (size_t)row*Kd + k0 + (c<<3));
        *reinterpret_cast<bf16x8*>(&As[r][(c ^ (r & 7)) << 3]) = v;
      }
    }
    #pragma unroll
    for (int it = 0; it < 2; it++){
      int sbase = (wv*2 + it) << 6;          // wave-uniform
      int s = sbase + lane;
      int r = s >> 3, cs = s & 7;
      const __bf16* gp = Bw + (size_t)(col0 + r)*Kd + k0 + ((cs ^ (r & 7)) << 3);
      __builtin_amdgcn_global_load_lds(gp, bs_flat + ((size_t)sbase << 3), 16, 0, 0);
    }
    __syncthreads();
    #pragma unroll
    for (int kk = 0; kk < 2; kk++){
      int kc = (kk << 2) + (lane >> 4);
      int ra0 = wm + (lane & 15), ra1 = ra0 + 16;
      int rb0 = wn + (lane & 15), rb1 = rb0 + 16;
      bf16x8 a0 = *reinterpret_cast<const bf16x8*>(&As[ra0][(kc ^ (ra0 & 7)) << 3]);
      bf16x8 a1 = *reinterpret_cast<const bf16x8*>(&As[ra1][(kc ^ (ra1 & 7)) << 3]);
      bf16x8 b0 = *reinterpret_cast<const bf16x8*>(&Bs[rb0][(kc ^ (rb0 & 7)) << 3]);
      bf16x8 b1 = *reinterpret_cast<const bf16x8*>(&Bs[rb1][(kc ^ (rb1 & 7)) << 3]);
      acc[0][0] = __builtin_amdgcn_mfma_f32_16x16x32_bf16(a0, b0, acc[0][0], 0, 0, 0);
      acc[0][1] = __builtin_amdgcn_mfma_f32_16x16x32_bf16(a0, b1, acc[0][1], 0, 0, 0);
      acc[1][0] = __builtin_amdgcn_mfma_f32_16x16x32_bf16(a1, b0, acc[1][0], 0, 0, 0);
      acc[1][1] = __builtin_amdgcn_mfma_f32_16x16x32_bf16(a1, b1, acc[1][1], 0, 0, 0);
    }
    __syncthreads();
  }
  #pragma unroll
  for (int mi = 0; mi < 2; mi++)
    #pragma unroll
    for (int ni = 0; ni < 2; ni++){
      int col = col0 + wn + (ni << 4) + (lane & 15);
      float bv = bias ? ((col < 256) ? bias[col] : bias2[col - 256]) : 0.f;
      int rowb = row0 + wm + (mi << 4) + ((lane >> 4) << 2);
      if (Ct){
        float* dst = Ct + ((size_t)(col >> 2) << 11) + (col & 3);
        #pragma unroll
        for (int e = 0; e < 4; e++){
          int row = rowb + e;
          if (row < M) dst[row << 2] = acc[mi][ni][e] + bv;
        }
      } else {
        #pragma unroll
        for (int e = 0; e < 4; e++){
          int row = rowb + e;
          if (row < M) C[(size_t)row*N + col] = acc[mi][ni][e] + bv;
        }
      }
    }
}

// ---------------------------------------------------------------------------
// Batched tail GEMMs: [0,64) cum | [64,192) c_lin/p_lin fused | [192,224) pos.
// ---------------------------------------------------------------------------
__global__ __launch_bounds__(256) void k_gemm3(
    const __bf16* __restrict__ Xb_u, const __bf16* __restrict__ Wcum_b,
    const float* __restrict__ bcum, float* __restrict__ cum,
    const __bf16* __restrict__ hb_fin, const __bf16* __restrict__ Wc_b,
    const float* __restrict__ bc, const float* __restrict__ bp,
    float* __restrict__ cp_lin,
    const __bf16* __restrict__ pe_b, const __bf16* __restrict__ Wr_b,
    const float* __restrict__ br, float* __restrict__ pos_t)
{
  __shared__ __align__(16) __bf16 As[64][64];
  __shared__ __align__(16) __bf16 Bs[64][64];
  int blk = blockIdx.x, tid = threadIdx.x;
  if (blk < 64){
    gemm_body(As, Bs, Xb_u, Wcum_b, bcum, bcum, cum, nullptr,
              1024, 256, 1024, (blk & 15) << 6, (blk >> 4) << 6, tid);
  } else if (blk < 192){
    int s = blk - 64;
    gemm_body(As, Bs, hb_fin, Wc_b, bc, bp, cp_lin, nullptr,
              1024, 512, 1024, (s & 15) << 6, (s >> 4) << 6, tid);
  } else {
    int s = blk - 192;
    gemm_body(As, Bs, pe_b, Wr_b, br, br, nullptr, pos_t,
              511, 256, 1024, (s & 7) << 6, (s >> 3) << 6, tid);
  }
}

// ---------------------------------------------------------------------------
// Cross-term GEMMs for LN-stat decomposition:
// [0,64) G1 | [64,192) G2 = ci·pos | [192,320) G3 = pj·pos.
// ---------------------------------------------------------------------------
__global__ __launch_bounds__(256) void k_gemm_cross(
    const __bf16* __restrict__ ci_bf, const __bf16* __restrict__ pj_bf,
    const __bf16* __restrict__ pos_bf,
    float* __restrict__ G1, float* __restrict__ G2, float* __restrict__ G3)
{
  __shared__ __align__(16) __bf16 As[64][64];
  __shared__ __align__(16) __bf16 Bs[64][64];
  int blk = blockIdx.x, tid = threadIdx.x;
  if (blk < 64){
    int b = blk >> 4, s = blk & 15;
    gemm_body(As, Bs, ci_bf + ((size_t)b << 16), pj_bf + ((size_t)b << 16),
              nullptr, nullptr, G1 + ((size_t)b << 16), nullptr,
              256, 256, 256, (s & 3) << 6, (s >> 2) << 6, tid);
  } else if (blk < 192){
    int s = blk - 64;
    gemm_body(As, Bs, ci_bf, pos_bf, nullptr, nullptr, G2, nullptr,
              1024, 512, 256, (s & 15) << 6, (s >> 4) << 6, tid);
  } else {
    int s = blk - 192;
    gemm_body(As, Bs, pj_bf, pos_bf, nullptr, nullptr, G3, nullptr,
              1024, 512, 256, (s & 15) << 6, (s >> 4) << 6, tid);
  }
}

// ---------------------------------------------------------------------------
// Conv layer, z-split x4 (256 channels each), XCD-contiguous block swizzle.
// B-stage + A-interior rows via global_load_lds; halo rows via register path.
// ---------------------------------------------------------------------------
__global__ __launch_bounds__(256) void k_conv_mfma(const __bf16* __restrict__ hb,
                                                   const __bf16* __restrict__ wbc,
                                                   __bf16* __restrict__ y, int layer)
{
  __shared__ __align__(16) __bf16 As[66][64];
  __shared__ __align__(16) __bf16 Bs[3][64][64];
  int tid = threadIdx.x;
  int lane = tid & 63, wave = tid >> 6;
  int wv = __builtin_amdgcn_readfirstlane(wave);
  int wm = (wave >> 1) << 5, wn = (wave & 1) << 5;
  int n = blockIdx.x;
  int swz = (n & 7)*128 + (n >> 3);      // XCD k handles contiguous swz chunk
  int bx = swz & 15, oy = (swz >> 4) & 15, z = swz >> 8;
  int b = bx >> 2, l0 = (bx & 3) << 6;
  int o0 = oy << 6;
  __bf16* as_flat = &As[0][0];
  __bf16* bs_flat = &Bs[0][0][0];
  f32x4 acc[2][2] = {};
  for (int cc = 0; cc < 4; cc++){
    int c0 = (z << 8) + (cc << 6);
    #pragma unroll
    for (int it = 0; it < 6; it++){
      int m = wv*6 + it;
      int s = (m << 6) + lane;
      int t = s >> 9, r = (s >> 3) & 63, c_ = s & 7;
      const __bf16* gp = wbc + ((size_t)((layer*3 + t) << 10) + o0 + r)*1024
                       + c0 + ((c_ ^ (r & 7)) << 3);
      __builtin_amdgcn_global_load_lds(gp, bs_flat + ((size_t)m << 9), 16, 0, 0);
    }
    #pragma unroll
    for (int it = 0; it < 2; it++){
      int sbase = (wv*2 + it) << 6;
      int s = sbase + lane;
      int r = 1 + (s >> 3), c = s & 7;
      const __bf16* gp = hb + (((size_t)(b<<8) + l0 - 1 + r) << 10)
                       + c0 + ((c ^ (r & 7)) << 3);
      __builtin_amdgcn_global_load_lds(gp, as_flat + 64 + ((size_t)sbase << 3), 16, 0, 0);
    }
    if (tid < 16){
      int rr = (tid >> 3) ? 65 : 0;
      int c = tid & 7;
      int l = l0 - 1 + rr;
      bf16x8 v = {};
      if (l >= 0 && l < L_)
        v = *reinterpret_cast<const bf16x8*>(hb + (((size_t)(b<<8) + l) << 10) + c0 + (c<<3));
      *reinterpret_cast<bf16x8*>(&As[rr][(c ^ (rr & 7)) << 3]) = v;
    }
    __syncthreads();
    #pragma unroll
    for (int t = 0; t < 3; t++){
      #pragma unroll
      for (int kk = 0; kk < 2; kk++){
        int kc = (kk << 2) + (lane >> 4);
        int ra0 = wm + (lane & 15) + t, ra1 = ra0 + 16;
        int rb0 = wn + (lane & 15),     rb1 = rb0 + 16;
        bf16x8 a0 = *reinterpret_cast<const bf16x8*>(&As[ra0][(kc ^ (ra0 & 7)) << 3]);
        bf16x8 a1 = *reinterpret_cast<const bf16x8*>(&As[ra1][(kc ^ (ra1 & 7)) << 3]);
        bf16x8 b0 = *reinterpret_cast<const bf16x8*>(&Bs[t][rb0][(kc ^ (rb0 & 7)) << 3]);
        bf16x8 b1 = *reinterpret_cast<const bf16x8*>(&Bs[t][rb1][(kc ^ (rb1 & 7)) << 3]);
        acc[0][0] = __builtin_amdgcn_mfma_f32_16x16x32_bf16(a0, b0, acc[0][0], 0, 0, 0);
        acc[0][1] = __builtin_amdgcn_mfma_f32_16x16x32_bf16(a0, b1, acc[0][1], 0, 0, 0);
        acc[1][0] = __builtin_amdgcn_mfma_f32_16x16x32_bf16(a1, b0, acc[1][0], 0, 0, 0);
        acc[1][1] = __builtin_amdgcn_mfma_f32_16x16x32_bf16(a1, b1, acc[1][1], 0, 0, 0);
      }
    }
    __syncthreads();
  }
  __bf16* yz = y + (size_t)z * 1048576;
  #pragma unroll
  for (int mi = 0; mi < 2; mi++)
    #pragma unroll
    for (int ni = 0; ni < 2; ni++){
      int col = o0 + wn + (ni << 4) + (lane & 15);
      #pragma unroll
      for (int e = 0; e < 4; e++){
        int rowl = wm + (mi << 4) + ((lane >> 4) << 2) + e;
        yz[(((size_t)(b<<8) + l0 + rowl) << 10) + col] = (__bf16)acc[mi][ni][e];
      }
    }
}

// ---------------------------------------------------------------------------
// LN(1024)+tanh over sum of 4 bf16 partials + bias.
// ---------------------------------------------------------------------------
__device__ __forceinline__ void ln_core4(const __bf16* y, const float* cb, int n, int tid,
                                         int lane, int wid, float* red,
                                         float4& v, float& mu, float& rstd){
  const __bf16* yr = y + ((size_t)n << 10) + tid*4;
  bf16x4 a0 = *reinterpret_cast<const bf16x4*>(yr);
  bf16x4 a1 = *reinterpret_cast<const bf16x4*>(yr + 1048576);
  bf16x4 a2 = *reinterpret_cast<const bf16x4*>(yr + 2097152);
  bf16x4 a3 = *reinterpret_cast<const bf16x4*>(yr + 3145728);
  float4 bb = ld4(cb + tid*4);
  v = make_float4((float)a0[0]+(float)a1[0]+(float)a2[0]+(float)a3[0]+bb.x,
                  (float)a0[1]+(float)a1[1]+(float)a2[1]+(float)a3[1]+bb.y,
                  (float)a0[2]+(float)a1[2]+(float)a2[2]+(float)a3[2]+bb.z,
                  (float)a0[3]+(float)a1[3]+(float)a2[3]+(float)a3[3]+bb.w);
  float s = v.x+v.y+v.z+v.w;
  #pragma unroll
  for (int m=1;m<64;m<<=1) s += __shfl_xor(s, m);
  if (lane == 0) red[wid] = s;
  __syncthreads();
  mu = (red[0]+red[1]+red[2]+red[3]) * (1.f/D_);
  float d0=v.x-mu, d1=v.y-mu, d2=v.z-mu, d3=v.w-mu;
  float ss = d0*d0+d1*d1+d2*d2+d3*d3;
  #pragma unroll
  for (int m=1;m<64;m<<=1) ss += __shfl_xor(ss, m);
  if (lane == 0) red[8+wid] = ss;
  __syncthreads();
  rstd = rsqrtf((red[8]+red[9]+red[10]+red[11]) * (1.f/D_) + 1e-5f);
}

__global__ __launch_bounds__(256) void k_ln_tanh_mid(const __bf16* __restrict__ y,
                                                     const float* __restrict__ cb,
                                                     const unsigned char* __restrict__ mask,
                                                     __bf16* __restrict__ hb)
{
  __shared__ float red[16];
  int n = blockIdx.x;
  int tid = threadIdx.x, lane = tid & 63, wid = tid >> 6;
  float4 v; float mu, rstd;
  ln_core4(y, cb, n, tid, lane, wid, red, v, mu, rstd);
  int stride = mask_stride(mask);
  float keep = mask_at(mask, stride, n) ? 1.f : 0.f;
  bf16x4 o;
  o[0] = (__bf16)(fast_tanh((v.x-mu)*rstd) * keep);
  o[1] = (__bf16)(fast_tanh((v.y-mu)*rstd) * keep);
  o[2] = (__bf16)(fast_tanh((v.z-mu)*rstd) * keep);
  o[3] = (__bf16)(fast_tanh((v.w-mu)*rstd) * keep);
  *reinterpret_cast<bf16x4*>(hb + ((size_t)n<<10) + tid*4) = o;
}

__global__ __launch_bounds__(256) void k_ln_tanh_fin(const __bf16* __restrict__ y,
                                                     const float* __restrict__ cb,
                                                     float* __restrict__ hf,
                                                     __bf16* __restrict__ hb)
{
  __shared__ float red[16];
  int n = blockIdx.x;
  int tid = threadIdx.x, lane = tid & 63, wid = tid >> 6;
  float4 v; float mu, rstd;
  ln_core4(y, cb, n, tid, lane, wid, red, v, mu, rstd);
  float t0 = fast_tanh((v.x-mu)*rstd), t1 = fast_tanh((v.y-mu)*rstd);
  float t2 = fast_tanh((v.z-mu)*rstd), t3 = fast_tanh((v.w-mu)*rstd);
  st4(&hf[((size_t)n<<10) + tid*4], make_float4(t0,t1,t2,t3));
  bf16x4 o; o[0]=(__bf16)t0; o[1]=(__bf16)t1; o[2]=(__bf16)t2; o[3]=(__bf16)t3;
  *reinterpret_cast<bf16x4*>(hb + ((size_t)n<<10) + tid*4) = o;
}

// ---------------------------------------------------------------------------
// Combine: masked cumsum + fold. ci row-major; pj transposed-packed
// pjt[k4][b][j][4]. Mask decoded to LDS flags (same b for all 4 waves).
// ---------------------------------------------------------------------------
__global__ __launch_bounds__(256) void k_combine(const float* __restrict__ cum,
                                                 const float* __restrict__ cp,
                                                 const unsigned char* __restrict__ mask,
                                                 float* __restrict__ ci,
                                                 float* __restrict__ pjt)
{
  __shared__ unsigned char mflag[256];
  int tid = threadIdx.x;
  int b = blockIdx.x >> 6;
  {
    int stride = mask_stride(mask);
    mflag[tid] = mask_at(mask, stride, (b << 8) + tid) ? 1 : 0;
  }
  __syncthreads();
  int w = blockIdx.x*4 + (tid >> 6);
  int lane = tid & 63;
  int k = w & 255;
  int rowbase = b << 8;
  float v[4], p[4];
  float run = 0.f;
  #pragma unroll
  for (int e = 0; e < 4; e++){
    int l = lane*4 + e;
    float x = cum[(((size_t)rowbase + l) << 8) + k];
    v[e] = mflag[l] ? 0.f : x;
    run += v[e]; p[e] = run;
  }
  float t = run, s = run;
  #pragma unroll
  for (int off = 1; off < 64; off <<= 1){
    float u = __shfl_up(s, off);
    if (lane >= off) s += u;
  }
  float excl = s - t;
  float total = __shfl(s, 63);
  float* pjb = pjt + (((size_t)((k >> 2)*4 + b)) << 10) + (k & 3);
  #pragma unroll
  for (int e = 0; e < 4; e++){
    int l = lane*4 + e;
    size_t row = rowbase + l;
    float f_ex = excl + p[e] - v[e];
    float b_in = total - (excl + p[e]);
    ci[(row << 8) + k] = cp[row*512 + k] + f_ex;
    pjb[l << 2] = cp[row*512 + 256 + k] - b_in;
  }
}

// ---------------------------------------------------------------------------
// Row stats + bf16 copies: wave per row. [0,1024) ci | [1024,2048) pj |
// [2048,2560) pos (row 511 zeroed).
// ---------------------------------------------------------------------------
__global__ __launch_bounds__(256) void k_rowstats(const float* __restrict__ ci,
                                                  const float* __restrict__ pjt,
                                                  const float* __restrict__ post,
                                                  __bf16* __restrict__ ci_bf,
                                                  __bf16* __restrict__ pj_bf,
                                                  __bf16* __restrict__ pos_bf,
                                                  float* __restrict__ stats)
{
  int w = blockIdx.x*4 + (threadIdx.x >> 6);
  int lane = threadIdx.x & 63;
  float4 v; __bf16* dst; float* Sp; float* Qp;
  if (w < 1024){
    v = ld4(&ci[((size_t)w << 8) + (lane << 2)]);
    dst = ci_bf + ((size_t)w << 8) + (lane << 2);
    Sp = stats + w; Qp = stats + 1024 + w;
  } else if (w < 2048){
    int row = w - 1024;
    int b = row >> 8, j = row & 255;
    v = ld4(pjt + ((size_t)lane << 12) + (b << 10) + (j << 2));
    dst = pj_bf + ((size_t)row << 8) + (lane << 2);
    Sp = stats + 2048 + row; Qp = stats + 3072 + row;
  } else {
    int d = w - 2048;
    if (d < 511) v = ld4(post + ((size_t)lane << 11) + (d << 2));
    else         v = make_float4(0.f, 0.f, 0.f, 0.f);
    dst = pos_bf + ((size_t)d << 8) + (lane << 2);
    Sp = stats + 4096 + d; Qp = stats + 4608 + d;
  }
  bf16x4 o; o[0]=(__bf16)v.x; o[1]=(__bf16)v.y; o[2]=(__bf16)v.z; o[3]=(__bf16)v.w;
  *reinterpret_cast<bf16x4*>(dst) = o;
  float s = v.x+v.y+v.z+v.w;
  float qv = v.x*v.x + v.y*v.y + v.z*v.z + v.w*v.w;
  #pragma unroll
  for (int m = 1; m < 64; m <<= 1){
    s  += __shfl_xor(s,  m);
    qv += __shfl_xor(qv, m);
  }
  if (lane == 0){ *Sp = s; *Qp = qv; }
}

// ---------------------------------------------------------------------------
// Pair kernel v10: single pass, precomputed stats, 4 threads per pair.
// Wave-uniform operands (ci row, ln_g/ln_b, wot) read from global with
// readfirstlane-hoisted uniform addresses -> scalar-pipe loads.
// ---------------------------------------------------------------------------
__global__ __launch_bounds__(256) void k_pairs(const float* __restrict__ ci,
                                               const float* __restrict__ pjt,
                                               const float* __restrict__ post,
                                               const float* __restrict__ ln_g,
                                               const float* __restrict__ ln_b,
                                               const float* __restrict__ wot,
                                               const float* __restrict__ bo,
                                               const unsigned char* __restrict__ mask,
                                               const float* __restrict__ stats,
                                               const float* __restrict__ G1,
                                               const float* __restrict__ G2,
                                               const float* __restrict__ G3,
                                               float* __restrict__ out)
{
  __shared__ float pacc[64][3][9];

  int bid = blockIdx.x;
  int qtr = bid & 3;
  int bi = bid >> 2;                 // b*256 + i
  int b = bi >> 8, i = bi & 255;
  int tid = threadIdx.x;
  int jj = tid & 63, q = tid >> 6;
  int j = (qtr << 6) + jj;

  int d = i - j + 255;
  int bj = (b << 8) + j;
  const float* pjb = pjt + ((size_t)b << 10) + (j << 2);
  const float* pob = post + ((size_t)d << 2);
  const float* cbase = ci + ((size_t)bi << 8);
  int k40 = __builtin_amdgcn_readfirstlane(q << 4);   // wave-uniform base

  // stats via decomposition
  float Sh = stats[bi] + stats[2048 + bj] + stats[4096 + d];
  float Qh = stats[1024 + bi] + stats[3072 + bj] + stats[4608 + d]
           + 2.f*(G1[((size_t)b << 16) + (i << 8) + j]
                + G2[((size_t)bi << 9) + d]
                + G3[((size_t)bj << 9) + d]);
  float mu = Sh * (1.f/256.f);
  float var = fmaxf(Qh * (1.f/256.f) - mu*mu, 0.f);
  float rstd = rsqrtf(var + 1e-5f);

  // single pass: h -> LN -> tanh -> packed projection
  f32x2 aP0={0,0},aP1={0,0},aP2={0,0},aP3={0,0},aP4={0,0},aP5={0,0},aP6={0,0},aP7={0,0};
  f32x2 mmu = {-mu, -mu}, rr = {rstd, rstd};
  #pragma unroll 4
  for (int u = 0; u < 16; u++){
    int k4 = k40 + u;
    float4 c4 = ld4(cbase + (k4 << 2));          // uniform -> scalar pipe
    float4 g4 = ld4(ln_g + (k4 << 2));           // uniform
    float4 b4 = ld4(ln_b + (k4 << 2));           // uniform
    float4 pv = ld4(pjb + ((size_t)k4 << 12));   // per-lane
    float4 ov = ld4(pob + ((size_t)k4 << 11));   // per-lane
    const float* wf = wot + (k4 << 5);           // uniform, 32 floats
    float4 w0 = ld4(wf),      float4_w1 = ld4(wf + 4);
    float4 w1 = float4_w1;
    float4 w2 = ld4(wf + 8),  w3 = ld4(wf + 12);
    float4 w4 = ld4(wf + 16), w5 = ld4(wf + 20);
    float4 w6 = ld4(wf + 24), w7 = ld4(wf + 28);
    f32x2 hA = (f32x2){c4.x, c4.y} + (f32x2){pv.x, pv.y} + (f32x2){ov.x, ov.y};
    f32x2 hB = (f32x2){c4.z, c4.w} + (f32x2){pv.z, pv.w} + (f32x2){ov.z, ov.w};
    f32x2 gA = {g4.x, g4.y}, gB = {g4.z, g4.w};
    f32x2 bA = {b4.x, b4.y}, bB = {b4.z, b4.w};
    f32x2 argA = ((hA + mmu) * rr) * gA + bA;
    f32x2 argB = ((hB + mmu) * rr) * gB + bB;
    f32x2 vA = fast_tanh2(argA);
    f32x2 vB = fast_tanh2(argB);
    aP0 = vA * (f32x2){w0.x, w0.y} + aP0;  aP1 = vA * (f32x2){w0.z, w0.w} + aP1;
    aP2 = vA * (f32x2){w1.x, w1.y} + aP2;  aP3 = vA * (f32x2){w1.z, w1.w} + aP3;
    aP4 = vA * (f32x2){w2.x, w2.y} + aP4;  aP5 = vA * (f32x2){w2.z, w2.w} + aP5;
    aP6 = vA * (f32x2){w3.x, w3.y} + aP6;  aP7 = vA * (f32x2){w3.z, w3.w} + aP7;
    aP0 = vB * (f32x2){w4.x, w4.y} + aP0;  aP1 = vB * (f32x2){w4.z, w4.w} + aP1;
    aP2 = vB * (f32x2){w5.x, w5.y} + aP2;  aP3 = vB * (f32x2){w5.z, w5.w} + aP3;
    aP4 = vB * (f32x2){w6.x, w6.y} + aP4;  aP5 = vB * (f32x2){w6.z, w6.w} + aP5;
    aP6 = vB * (f32x2){w7.x, w7.y} + aP6;  aP7 = vB * (f32x2){w7.z, w7.w} + aP7;
  }
  float a0 = aP0[0]+aP0[1], a1 = aP1[0]+aP1[1];
  float a2 = aP2[0]+aP2[1], a3 = aP3[0]+aP3[1];
  float a4 = aP4[0]+aP4[1], a5 = aP5[0]+aP5[1];
  float a6 = aP6[0]+aP6[1], a7 = aP7[0]+aP7[1];
  if (q){
    float* pp = &pacc[jj][q-1][0];
    pp[0]=a0; pp[1]=a1; pp[2]=a2; pp[3]=a3;
    pp[4]=a4; pp[5]=a5; pp[6]=a6; pp[7]=a7;
  }
  __syncthreads();
  if (!q){
    const float* p0 = &pacc[jj][0][0];
    const float* p1 = &pacc[jj][1][0];
    const float* p2 = &pacc[jj][2][0];
    a0 += p0[0]+p1[0]+p2[0]; a1 += p0[1]+p1[1]+p2[1];
    a2 += p0[2]+p1[2]+p2[2]; a3 += p0[3]+p1[3]+p2[3];
    a4 += p0[4]+p1[4]+p2[4]; a5 += p0[5]+p1[5]+p2[5];
    a6 += p0[6]+p1[6]+p2[6]; a7 += p0[7]+p1[7]+p2[7];
    float acc[8] = {a0,a1,a2,a3,a4,a5,a6,a7};
    int stride = mask_stride(mask);
    bool vis = mask_at(mask, stride, bi) && mask_at(mask, stride, bj);
    float res[8];
    #pragma unroll
    for (int r = 0; r < 8; r++){
      float sc = (acc[r] + bo[r]) * (1.f/7.5f);
      res[r] = vis ? fast_tanh(sc)*7.5f : -64.f;
    }
    float* lp = out + (((size_t)bi << 8) + j)*8;
    st4(lp,     make_float4(res[0],res[1],res[2],res[3]));
    st4(lp + 4, make_float4(res[4],res[5],res[6],res[7]));
    if (j == i){
      float* rp = out + (size_t)B_*L_*L_*R_ + ((size_t)bi)*8;
      st4(rp,     make_float4(res[0],res[1],res[2],res[3]));
      st4(rp + 4, make_float4(res[4],res[5],res[6],res[7]));
    }
  }
}

// ---------------------------------------------------------------------------
extern "C" void kernel_launch(void* const* d_in, const int* in_sizes, int n_in,
                              void* d_out, int out_size, void* d_ws, size_t ws_size,
                              hipStream_t stream)
{
  const float* X      = (const float*)d_in[0];
  const float* conv_w = (const float*)d_in[1];
  const float* conv_b = (const float*)d_in[2];
  const float* Wc     = (const float*)d_in[3];
  const float* bc     = (const float*)d_in[4];
  const float* Wp     = (const float*)d_in[5];
  const float* bp     = (const float*)d_in[6];
  const float* Wcum   = (const float*)d_in[7];
  const float* bcum   = (const float*)d_in[8];
  const float* Wr     = (const float*)d_in[9];
  const float* br     = (const float*)d_in[10];
  const float* ln_g   = (const float*)d_in[11];
  const float* ln_b   = (const float*)d_in[12];
  const float* Wo     = (const float*)d_in[13];
  const float* bo     = (const float*)d_in[14];
  const unsigned char* mask = (const unsigned char*)d_in[15];
  float* out = (float*)d_out;

  char* base = (char*)d_ws;
  auto alloc = [&](size_t bytes){ char* p = base; base += (bytes + 255) & ~(size_t)255; return p; };
  __bf16* Xb_u    = (__bf16*)alloc(2097152);
  __bf16* Xb_m    = (__bf16*)alloc(2097152);
  __bf16* Wbc     = (__bf16*)alloc(18874368);
  __bf16* Wcum_b  = (__bf16*)alloc(524288);
  __bf16* Wc_b    = (__bf16*)alloc(524288);   // contiguous with Wp_b -> [512][1024]
  __bf16* Wp_b    = (__bf16*)alloc(524288);
  __bf16* Wr_b    = (__bf16*)alloc(524288);
  __bf16* pe_b    = (__bf16*)alloc(1046528);
  __bf16* ypart   = (__bf16*)alloc(8388608);  // 4 x [1024][1024] bf16 partials
  __bf16* hb_mid  = (__bf16*)alloc(2097152);
  __bf16* hb_fin  = (__bf16*)alloc(2097152);
  float*  cum     = (float*) alloc(1048576);
  float*  cp_lin  = (float*) alloc(2097152);  // [1024][512]
  float*  ci_c    = (float*) alloc(1048576);  // [b][i][256]
  float*  pj_t    = (float*) alloc(1048576);  // [k4][b][j][4]
  float*  pos_t   = (float*) alloc(524288);   // [k4][512 d][4]
  __bf16* ci_bf   = (__bf16*)alloc(524288);   // [1024][256]
  __bf16* pj_bf   = (__bf16*)alloc(524288);   // [1024][256]
  __bf16* pos_bf  = (__bf16*)alloc(262144);   // [512][256]
  float*  statsB  = (float*) alloc(20480);    // S/Q rows (5120 f32)
  float*  G1      = (float*) alloc(1048576);  // [4][256][256]
  float*  G2      = (float*) alloc(2097152);  // [1024][512]
  float*  G3      = (float*) alloc(2097152);  // [1024][512]
  float*  wot     = (float*) alloc(8192);     // pair-interleaved Wo transpose
  (void)Wp_b;

  float* h_out = out + (size_t)B_*L_*L_*R_ + (size_t)B_*L_*R_;

  k_megaprep<<<4608, 256, 0, stream>>>(X, mask, Xb_u, Xb_m, conv_w, Wbc,
                                       Wcum, Wc, Wp, Wr, Wcum_b, Wc_b, Wp_b, Wr_b,
                                       pe_b, Wo, wot);

  // conv stack (z-split x4, XCD swizzle, glds staging, bias folded into LN)
  k_conv_mfma<<<1024, 256, 0, stream>>>(Xb_m,   Wbc, ypart, 0);
  k_ln_tanh_mid<<<B_*L_, 256, 0, stream>>>(ypart, conv_b,        mask, hb_mid);
  k_conv_mfma<<<1024, 256, 0, stream>>>(hb_mid, Wbc, ypart, 1);
  k_ln_tanh_mid<<<B_*L_, 256, 0, stream>>>(ypart, conv_b + 1024, mask, hb_mid);
  k_conv_mfma<<<1024, 256, 0, stream>>>(hb_mid, Wbc, ypart, 2);
  k_ln_tanh_fin<<<B_*L_, 256, 0, stream>>>(ypart, conv_b + 2048, h_out, hb_fin);

  // batched tail GEMMs: cum | c_lin/p_lin | pos
  k_gemm3<<<224, 256, 0, stream>>>(Xb_u, Wcum_b, bcum, cum,
                                   hb_fin, Wc_b, bc, bp, cp_lin,
                                   pe_b, Wr_b, br, pos_t);

  // cumsum + fold
  k_combine<<<256, 256, 0, stream>>>(cum, cp_lin, mask, ci_c, pj_t);

  // row stats + bf16 copies, then cross-term GEMMs
  k_rowstats<<<640, 256, 0, stream>>>(ci_c, pj_t, pos_t, ci_bf, pj_bf, pos_bf, statsB);
  k_gemm_cross<<<320, 256, 0, stream>>>(ci_bf, pj_bf, pos_bf, G1, G2, G3);

  // pairs (single pass, scalarized uniform operands)
  k_pairs<<<B_*L_*4, 256, 0, stream>>>(ci_c, pj_t, pos_t, ln_g, ln_b, wot, bo,
                                       mask, statsB, G1, G2, G3, out);
}